// Round 3
// baseline (979.628 us; speedup 1.0000x reference)
//
#include <hip/hip_runtime.h>
#include <math.h>

#define B_ 64
#define T_ 1024
#define D_ 256
#define U_ 256

// ---------------------------------------------------------------------------
// Kernel 1: proj = inputs @ W_xh + b_h, written into d_out (reused as xW buf).
// Classic fp32 tile GEMM: 64x64 tile, BK=16, 256 threads, 4x4 micro-tile.
// (unchanged this round — isolate the rnn_scan register fix)
// ---------------------------------------------------------------------------
#define BM 64
#define BN 64
#define BK 16

__global__ __launch_bounds__(256, 2)
void proj_gemm(const float* __restrict__ A,      // [M, D_] inputs
               const float* __restrict__ Bm,     // [D_, U_] W_xh
               const float* __restrict__ bias,   // [U_]
               float* __restrict__ C) {          // [M, U_] out
    __shared__ float As[BK][BM];   // transposed A tile: As[k][m]
    __shared__ float Bs[BK][BN];

    const int m0 = blockIdx.x * BM;
    const int n0 = blockIdx.y * BN;
    const int tid = (int)threadIdx.x;
    const int tx = tid & 15;        // output col group
    const int ty = tid >> 4;        // output row group

    const int ar  = tid >> 2;       // 0..63
    const int akq = tid & 3;        // 0..3 (float4 along k)
    const int bk  = tid >> 4;       // 0..15
    const int bnq = tid & 15;       // 0..15 (float4 along n)

    float acc[4][4] = {};

    for (int k0 = 0; k0 < D_; k0 += BK) {
        float4 av = *(const float4*)&A[(size_t)(m0 + ar) * D_ + k0 + akq * 4];
        float4 bv = *(const float4*)&Bm[(size_t)(k0 + bk) * U_ + n0 + bnq * 4];
        __syncthreads();
        As[akq * 4 + 0][ar] = av.x;
        As[akq * 4 + 1][ar] = av.y;
        As[akq * 4 + 2][ar] = av.z;
        As[akq * 4 + 3][ar] = av.w;
        *(float4*)&Bs[bk][bnq * 4] = bv;
        __syncthreads();
        #pragma unroll
        for (int kk = 0; kk < BK; ++kk) {
            float4 a = *(const float4*)&As[kk][ty * 4];
            float4 b = *(const float4*)&Bs[kk][tx * 4];
            acc[0][0] = fmaf(a.x, b.x, acc[0][0]);
            acc[0][1] = fmaf(a.x, b.y, acc[0][1]);
            acc[0][2] = fmaf(a.x, b.z, acc[0][2]);
            acc[0][3] = fmaf(a.x, b.w, acc[0][3]);
            acc[1][0] = fmaf(a.y, b.x, acc[1][0]);
            acc[1][1] = fmaf(a.y, b.y, acc[1][1]);
            acc[1][2] = fmaf(a.y, b.z, acc[1][2]);
            acc[1][3] = fmaf(a.y, b.w, acc[1][3]);
            acc[2][0] = fmaf(a.z, b.x, acc[2][0]);
            acc[2][1] = fmaf(a.z, b.y, acc[2][1]);
            acc[2][2] = fmaf(a.z, b.z, acc[2][2]);
            acc[2][3] = fmaf(a.z, b.w, acc[2][3]);
            acc[3][0] = fmaf(a.w, b.x, acc[3][0]);
            acc[3][1] = fmaf(a.w, b.y, acc[3][1]);
            acc[3][2] = fmaf(a.w, b.z, acc[3][2]);
            acc[3][3] = fmaf(a.w, b.w, acc[3][3]);
        }
    }

    const float4 bb = *(const float4*)&bias[n0 + tx * 4];
    #pragma unroll
    for (int i = 0; i < 4; ++i) {
        const int row = m0 + ty * 4 + i;
        float4 o;
        o.x = acc[i][0] + bb.x;
        o.y = acc[i][1] + bb.y;
        o.z = acc[i][2] + bb.z;
        o.w = acc[i][3] + bb.w;
        *(float4*)&C[(size_t)row * U_ + n0 + tx * 4] = o;
    }
}

// ---------------------------------------------------------------------------
// fast tanh: sign(x) * (1 - 2/(exp(2|x|)+1)); |2x| clamped to 20
// (tanh(10) = 1-4e-9, far below the 2e-2 absmax threshold).
// v_exp + v_rcp (quarter-rate) instead of libm tanhf's branchy sequence.
// ---------------------------------------------------------------------------
__device__ __forceinline__ float fast_tanh(float x) {
    float a = fminf(fabsf(x) * 2.0f, 20.0f);
    float e = __expf(a);
    float t = 1.0f - 2.0f * __builtin_amdgcn_rcpf(e + 1.0f);
    return copysignf(t, x);
}

// ---------------------------------------------------------------------------
// Kernel 2: sequential recurrence, one block per batch element.
// 512 threads = 8 waves (2/SIMD). Wave g owns k-range [g*32, g*32+32);
// lane l owns u-columns [4l, 4l+4). Per-thread W_hh slice: 32 x float4
// = 128 VGPRs, PINNED via empty inline asm — round 2 showed VGPR_Count=84,
// i.e. the allocator spilled/reloaded the slice every step (~2x VALU work).
// The "+v" pin makes each component an opaque VGPR def the compiler cannot
// rematerialize; budget at __launch_bounds__(512,2) is 256 regs, so ~150
// live fits without spill.
// ---------------------------------------------------------------------------
#define NT_  512
#define KG_  8
#define KPT_ 32

__global__ __launch_bounds__(NT_, 2)
void rnn_scan(const float* __restrict__ W_hh,   // [U_, U_]
              float* __restrict__ out) {        // [B_, T_, U_]: xW in, h out
    const int b    = (int)blockIdx.x;
    const int tid  = (int)threadIdx.x;
    const int kg   = tid >> 6;        // 0..7, wave-uniform k-group
    const int lane = tid & 63;
    const int u0   = lane * 4;        // u base (4 columns per thread)
    const int k0   = kg * KPT_;       // k base (32 rows per thread)

    __shared__ float h[2][U_];        // double-buffered hidden state
    __shared__ float part[KG_][U_];   // per-k-group partial sums

    // W_hh slice into registers: w4[k] = W_hh[k0+k][u0..u0+3], coalesced.
    float4 w4[KPT_];
    #pragma unroll
    for (int k = 0; k < KPT_; ++k)
        w4[k] = *(const float4*)&W_hh[(size_t)(k0 + k) * U_ + u0];
    // Pin the 128 floats into VGPRs (see header comment).
    #pragma unroll
    for (int k = 0; k < KPT_; ++k)
        asm volatile("" : "+v"(w4[k].x), "+v"(w4[k].y),
                          "+v"(w4[k].z), "+v"(w4[k].w));

    if (tid < U_) h[0][tid] = 0.0f;   // h[1] is written before first read

    // Finalize threads (tid < 256, u = tid) own column [b, :, u] of out.
    float* colp = out + (size_t)b * T_ * U_ + tid;
    float xw0 = 0.0f, xw1 = 0.0f;
    if (tid < U_) {
        xw0 = colp[0];                 // t = 0
        xw1 = colp[U_];                // t = 1
    }
    __syncthreads();

    int cur = 0;
    for (int t = 0; t < T_; ++t) {
        // ---- partial matvec: acc[j] = sum_{k in group} h[k] * W[k][u0+j]
        float4 acc = make_float4(0.f, 0.f, 0.f, 0.f);
        const float4* h4 = (const float4*)&h[cur][k0];  // wave-uniform addr
        #pragma unroll
        for (int kk = 0; kk < KPT_ / 4; ++kk) {
            const float4 hv = h4[kk];                    // LDS broadcast read
            const float4 wa = w4[4 * kk + 0];
            const float4 wb = w4[4 * kk + 1];
            const float4 wc = w4[4 * kk + 2];
            const float4 wd = w4[4 * kk + 3];
            acc.x = fmaf(hv.x, wa.x, acc.x);
            acc.y = fmaf(hv.x, wa.y, acc.y);
            acc.z = fmaf(hv.x, wa.z, acc.z);
            acc.w = fmaf(hv.x, wa.w, acc.w);
            acc.x = fmaf(hv.y, wb.x, acc.x);
            acc.y = fmaf(hv.y, wb.y, acc.y);
            acc.z = fmaf(hv.y, wb.z, acc.z);
            acc.w = fmaf(hv.y, wb.w, acc.w);
            acc.x = fmaf(hv.z, wc.x, acc.x);
            acc.y = fmaf(hv.z, wc.y, acc.y);
            acc.z = fmaf(hv.z, wc.z, acc.z);
            acc.w = fmaf(hv.z, wc.w, acc.w);
            acc.x = fmaf(hv.w, wd.x, acc.x);
            acc.y = fmaf(hv.w, wd.y, acc.y);
            acc.z = fmaf(hv.w, wd.z, acc.z);
            acc.w = fmaf(hv.w, wd.w, acc.w);
        }
        *(float4*)&part[kg][u0] = acc;   // conflict-free b128 write
        __syncthreads();

        // ---- finalize: 4 waves (tid < 256), u = tid
        if (tid < U_) {
            float s = xw0;
            #pragma unroll
            for (int g = 0; g < KG_; ++g)
                s += part[g][tid];       // stride-1 across lanes: no conflict
            // rotate the xW prefetch pipeline (distance 2 covers L2/HBM miss)
            xw0 = xw1;
            if (t + 2 < T_) xw1 = colp[(size_t)(t + 2) * U_];
            const float hn = fast_tanh(s);
            h[1 - cur][tid] = hn;
            colp[(size_t)t * U_] = hn;   // overwrite xW with h_t
        }
        cur ^= 1;
        __syncthreads();
    }
}

// ---------------------------------------------------------------------------
extern "C" void kernel_launch(void* const* d_in, const int* in_sizes, int n_in,
                              void* d_out, int out_size, void* d_ws, size_t ws_size,
                              hipStream_t stream) {
    const float* inputs = (const float*)d_in[0];   // [B, T, D]
    const float* W_xh   = (const float*)d_in[1];   // [D, U]
    const float* W_hh   = (const float*)d_in[2];   // [U, U]
    const float* b_h    = (const float*)d_in[3];   // [U]
    float* out = (float*)d_out;                    // [B, T, U]

    const int M = B_ * T_;                         // 65536
    dim3 g1(M / BM, U_ / BN);                      // (1024, 4)
    proj_gemm<<<g1, 256, 0, stream>>>(inputs, W_xh, b_h, out);
    rnn_scan<<<B_, NT_, 0, stream>>>(W_hh, out);
}

// Round 4
// 758.812 us; speedup vs baseline: 1.2910x; 1.2910x over previous
//
#include <hip/hip_runtime.h>
#include <math.h>

#define B_ 64
#define T_ 1024
#define D_ 256
#define U_ 256

typedef _Float16 h2_t __attribute__((ext_vector_type(2)));
typedef _Float16 h8_t __attribute__((ext_vector_type(8)));

// ---------------------------------------------------------------------------
// Kernel 1: proj = inputs @ W_xh + b_h, written into d_out (reused as xW buf).
// (unchanged — isolate the rnn_scan restructure this round)
// ---------------------------------------------------------------------------
#define BM 64
#define BN 64
#define BK 16

__global__ __launch_bounds__(256, 2)
void proj_gemm(const float* __restrict__ A,      // [M, D_] inputs
               const float* __restrict__ Bm,     // [D_, U_] W_xh
               const float* __restrict__ bias,   // [U_]
               float* __restrict__ C) {          // [M, U_] out
    __shared__ float As[BK][BM];   // transposed A tile: As[k][m]
    __shared__ float Bs[BK][BN];

    const int m0 = blockIdx.x * BM;
    const int n0 = blockIdx.y * BN;
    const int tid = (int)threadIdx.x;
    const int tx = tid & 15;
    const int ty = tid >> 4;

    const int ar  = tid >> 2;
    const int akq = tid & 3;
    const int bk  = tid >> 4;
    const int bnq = tid & 15;

    float acc[4][4] = {};

    for (int k0 = 0; k0 < D_; k0 += BK) {
        float4 av = *(const float4*)&A[(size_t)(m0 + ar) * D_ + k0 + akq * 4];
        float4 bv = *(const float4*)&Bm[(size_t)(k0 + bk) * U_ + n0 + bnq * 4];
        __syncthreads();
        As[akq * 4 + 0][ar] = av.x;
        As[akq * 4 + 1][ar] = av.y;
        As[akq * 4 + 2][ar] = av.z;
        As[akq * 4 + 3][ar] = av.w;
        *(float4*)&Bs[bk][bnq * 4] = bv;
        __syncthreads();
        #pragma unroll
        for (int kk = 0; kk < BK; ++kk) {
            float4 a = *(const float4*)&As[kk][ty * 4];
            float4 b = *(const float4*)&Bs[kk][tx * 4];
            acc[0][0] = fmaf(a.x, b.x, acc[0][0]);
            acc[0][1] = fmaf(a.x, b.y, acc[0][1]);
            acc[0][2] = fmaf(a.x, b.z, acc[0][2]);
            acc[0][3] = fmaf(a.x, b.w, acc[0][3]);
            acc[1][0] = fmaf(a.y, b.x, acc[1][0]);
            acc[1][1] = fmaf(a.y, b.y, acc[1][1]);
            acc[1][2] = fmaf(a.y, b.z, acc[1][2]);
            acc[1][3] = fmaf(a.y, b.w, acc[1][3]);
            acc[2][0] = fmaf(a.z, b.x, acc[2][0]);
            acc[2][1] = fmaf(a.z, b.y, acc[2][1]);
            acc[2][2] = fmaf(a.z, b.z, acc[2][2]);
            acc[2][3] = fmaf(a.z, b.w, acc[2][3]);
            acc[3][0] = fmaf(a.w, b.x, acc[3][0]);
            acc[3][1] = fmaf(a.w, b.y, acc[3][1]);
            acc[3][2] = fmaf(a.w, b.z, acc[3][2]);
            acc[3][3] = fmaf(a.w, b.w, acc[3][3]);
        }
    }

    const float4 bb = *(const float4*)&bias[n0 + tx * 4];
    #pragma unroll
    for (int i = 0; i < 4; ++i) {
        const int row = m0 + ty * 4 + i;
        float4 o;
        o.x = acc[i][0] + bb.x;
        o.y = acc[i][1] + bb.y;
        o.z = acc[i][2] + bb.z;
        o.w = acc[i][3] + bb.w;
        *(float4*)&C[(size_t)row * U_ + n0 + tx * 4] = o;
    }
}

// ---------------------------------------------------------------------------
// fast tanh (validated R3: absmax unchanged vs tanhf)
// ---------------------------------------------------------------------------
__device__ __forceinline__ float fast_tanh(float x) {
    float a = fminf(fabsf(x) * 2.0f, 20.0f);
    float e = __expf(a);
    float t = 1.0f - 2.0f * __builtin_amdgcn_rcpf(e + 1.0f);
    return copysignf(t, x);
}

// ---------------------------------------------------------------------------
// Kernel 2: recurrence. One block/batch, 512 threads = 8 waves (2/SIMD).
// Wave kg owns k-range [32kg,32kg+32); lane owns u-quad u0=4*lane.
// W slice held as f16 pairs: wreg[16][4] h2 = 64 VGPRs (half of the fp32
// version that the allocator refused to keep in arch VGPRs in R2/R3).
// Matvec via v_dot2_f32_f16 (fp32 accumulate): h in (-1,1), |w|<~0.25,
// per-step f16 error ~1e-3 << 2e-2 threshold; tanh contraction bounds it.
// T processed in 16-step LDS chunks (double-buffered): NO global ops inside
// the step loop, so the vmcnt(0)-drain at every __syncthreads stops costing
// ~300 cyc/step (now once per chunk). xW chunk is overwritten in place with
// h (same slot), dumped coalesced once per chunk.
// ---------------------------------------------------------------------------
#define CH_  16
#define NT2_ 512

__global__ __launch_bounds__(NT2_) __attribute__((amdgpu_waves_per_eu(2, 2)))
void rnn_scan(const float* __restrict__ W_hh,   // [U_, U_]
              float* __restrict__ out) {        // [B_, T_, U_]: xW in, h out
    const int b    = (int)blockIdx.x;
    const int tid  = (int)threadIdx.x;
    const int kg   = tid >> 6;        // wave 0..7: k-group (wave-uniform)
    const int lane = tid & 63;
    const int u0   = lane * 4;        // u-quad per lane
    const int k0   = kg * 32;

    __shared__ float buf[2][CH_][U_];   // xw in / h out (fp32), double-buffered
    __shared__ float part[8][U_];       // per-k-group partials
    __shared__ h2_t  hlds[U_ / 2];      // hidden state, f16 pairs

    // W_hh slice -> f16 pair registers: wreg[kk][c] = (W[k0+2kk][u0+c],
    // W[k0+2kk+1][u0+c]). Coalesced float4 row loads (1 KB/wave/row).
    h2_t wreg[16][4];
    #pragma unroll
    for (int kk = 0; kk < 16; ++kk) {
        const float4 ra = *(const float4*)&W_hh[(size_t)(k0 + 2 * kk) * U_ + u0];
        const float4 rb = *(const float4*)&W_hh[(size_t)(k0 + 2 * kk + 1) * U_ + u0];
        wreg[kk][0] = h2_t{(_Float16)ra.x, (_Float16)rb.x};
        wreg[kk][1] = h2_t{(_Float16)ra.y, (_Float16)rb.y};
        wreg[kk][2] = h2_t{(_Float16)ra.z, (_Float16)rb.z};
        wreg[kk][3] = h2_t{(_Float16)ra.w, (_Float16)rb.w};
    }

    if (tid < U_ / 2) hlds[tid] = h2_t{(_Float16)0.f, (_Float16)0.f};

    float* gbase = out + (size_t)b * T_ * U_;

    // load chunk 0 -> buf[0]  (flat 4096 floats, 8 per thread, coalesced)
    {
        float4 v0 = *(const float4*)&gbase[8 * tid];
        float4 v1 = *(const float4*)&gbase[8 * tid + 4];
        float* bf = &buf[0][0][0];
        *(float4*)&bf[8 * tid]     = v0;
        *(float4*)&bf[8 * tid + 4] = v1;
    }
    __syncthreads();

    int cur = 0;
    for (int c = 0; c < T_ / CH_; ++c) {
        // prefetch chunk c+1 into buf[1-cur]; completes during the 16 steps.
        // buf[1-cur] was dumped last iteration by the SAME thread at the SAME
        // addresses -> no cross-thread hazard; any step barrier orders the
        // ds_writes before next chunk's reads.
        if (c + 1 < T_ / CH_) {
            const float* gsrc = gbase + (size_t)(c + 1) * CH_ * U_;
            float4 v0 = *(const float4*)&gsrc[8 * tid];
            float4 v1 = *(const float4*)&gsrc[8 * tid + 4];
            float* bf = &buf[1 - cur][0][0];
            *(float4*)&bf[8 * tid]     = v0;
            *(float4*)&bf[8 * tid + 4] = v1;
        }

        for (int j = 0; j < CH_; ++j) {
            // ---- phase 1: partial matvec over this wave's 32 k
            float4 acc = make_float4(0.f, 0.f, 0.f, 0.f);
            const h8_t* h8 = (const h8_t*)&hlds[kg * 16];  // wave-uniform addr
            #pragma unroll
            for (int i = 0; i < 4; ++i) {
                h8_t hv = h8[i];                 // b128 broadcast: 8 h-values
                #pragma unroll
                for (int cc = 0; cc < 4; ++cc) {
                    h2_t hp = h2_t{hv[2 * cc], hv[2 * cc + 1]};
                    const int kk = 4 * i + cc;
                    acc.x = __builtin_amdgcn_fdot2(hp, wreg[kk][0], acc.x, false);
                    acc.y = __builtin_amdgcn_fdot2(hp, wreg[kk][1], acc.y, false);
                    acc.z = __builtin_amdgcn_fdot2(hp, wreg[kk][2], acc.z, false);
                    acc.w = __builtin_amdgcn_fdot2(hp, wreg[kk][3], acc.w, false);
                }
            }
            *(float4*)&part[kg][u0] = acc;       // b128, conflict-free
            __syncthreads();                     // A: partials ready

            // ---- finalize: 2 waves (tid<128), u-pair per lane, b64 LDS ops
            if (tid < 128) {
                float2 s = *(float2*)&buf[cur][j][2 * tid];   // xw (fp32)
                #pragma unroll
                for (int g = 0; g < 8; ++g) {
                    float2 p = *(float2*)&part[g][2 * tid];
                    s.x += p.x;
                    s.y += p.y;
                }
                const float hx = fast_tanh(s.x);
                const float hy = fast_tanh(s.y);
                *(float2*)&buf[cur][j][2 * tid] = make_float2(hx, hy);  // h out
                hlds[tid] = h2_t{(_Float16)hx, (_Float16)hy};           // b32
            }
            __syncthreads();                     // B: h ready for next step
        }

        // ---- dump chunk (now holding h) -> global, coalesced
        {
            float* gdst = gbase + (size_t)c * CH_ * U_;
            const float* bf = &buf[cur][0][0];
            float4 v0 = *(const float4*)&bf[8 * tid];
            float4 v1 = *(const float4*)&bf[8 * tid + 4];
            *(float4*)&gdst[8 * tid]     = v0;
            *(float4*)&gdst[8 * tid + 4] = v1;
        }
        cur ^= 1;
    }
}

// ---------------------------------------------------------------------------
extern "C" void kernel_launch(void* const* d_in, const int* in_sizes, int n_in,
                              void* d_out, int out_size, void* d_ws, size_t ws_size,
                              hipStream_t stream) {
    const float* inputs = (const float*)d_in[0];   // [B, T, D]
    const float* W_xh   = (const float*)d_in[1];   // [D, U]
    const float* W_hh   = (const float*)d_in[2];   // [U, U]
    const float* b_h    = (const float*)d_in[3];   // [U]
    float* out = (float*)d_out;                    // [B, T, U]

    const int M = B_ * T_;                         // 65536
    dim3 g1(M / BM, U_ / BN);                      // (1024, 4)
    proj_gemm<<<g1, 256, 0, stream>>>(inputs, W_xh, b_h, out);
    rnn_scan<<<B_, NT2_, 0, stream>>>(W_hh, out);
}